// Round 1
// baseline (4253.263 us; speedup 1.0000x reference)
//
#include <hip/hip_runtime.h>
#include <cstdint>
#include <cstddef>

#define TS 96
#define TSS 9216
#define CIN 64
#define KST 104   // padded bf16 row stride for K/Q (conflict-floor for per-lane row b128 reads)

__device__ __forceinline__ uint16_t f2bf(float x) {
  uint32_t u = __float_as_uint(x);
  uint32_t r = (u + 0x7fffu + ((u >> 16) & 1u)) >> 16;  // RNE
  return (uint16_t)r;
}

__device__ __forceinline__ void unpack8(uint4 u, float* f) {
  f[0] = __uint_as_float(u.x << 16);
  f[1] = __uint_as_float(u.x & 0xffff0000u);
  f[2] = __uint_as_float(u.y << 16);
  f[3] = __uint_as_float(u.y & 0xffff0000u);
  f[4] = __uint_as_float(u.z << 16);
  f[5] = __uint_as_float(u.z & 0xffff0000u);
  f[6] = __uint_as_float(u.w << 16);
  f[7] = __uint_as_float(u.w & 0xffff0000u);
}

// One block per (b, h, c): project v,q,k (fp32 -> bf16 LDS), scores, softmax, PV.
// attn_out layout: [b][c*8+h][x][z]  (matches reference transpose(0,2,1,3,4))
__global__ __launch_bounds__(256, 2) void attn_fused_kernel(
    const float* __restrict__ x, const float* __restrict__ w_vkq,
    const float* __restrict__ b_vkq, float* __restrict__ attn_out)
{
  __shared__ __align__(16) uint16_t Vs[TS * TS];    // 18432 B, broadcast reads
  __shared__ __align__(16) uint16_t Ks[TS * KST];   // 19968 B, per-lane row reads
  __shared__ __align__(16) uint16_t Qs[TS * KST];   // 19968 B
  __shared__ __align__(16) float hrow[4][4][TS];    // 6144 B, per-wave softmax rows
  // total 64512 B < 64 KiB static limit; 2 blocks/CU

  const int t   = threadIdx.x;
  const int blk = blockIdx.x;
  const int b   = blk >> 9;      // 512 blocks per batch (b-major -> XCD L2 shares x[b])
  const int hc  = blk & 511;     // h*64 + c
  const int h   = hc >> 6;
  const int c   = hc & 63;

  const float bv = b_vkq[hc];
  const float bq = b_vkq[512 + hc];
  const float bk = b_vkq[1024 + hc];
  const float* __restrict__ wvp = w_vkq + (size_t)hc * CIN;            // s=0 (v)
  const float* __restrict__ wqp = w_vkq + (size_t)(512 + hc) * CIN;    // s=1 (q)
  const float* __restrict__ wkp = w_vkq + (size_t)(1024 + hc) * CIN;   // s=2 (k)
  const float* __restrict__ xb  = x + (size_t)b * CIN * TSS;

  // ---- projection: v,q,k for all 9216 spatial positions (fp32 FMA) ----
  for (int sweep = 0; sweep < 9; ++sweep) {
    const int p4 = sweep * 1024 + t * 4;   // 4 consecutive positions, row-aligned (96%4==0)
    float av0=bv, av1=bv, av2=bv, av3=bv;
    float aq0=bq, aq1=bq, aq2=bq, aq3=bq;
    float ak0=bk, ak1=bk, ak2=bk, ak3=bk;
    #pragma unroll 4
    for (int cc = 0; cc < CIN; ++cc) {
      const float4 xv = *(const float4*)(xb + (size_t)cc * TSS + p4);
      const float wva = wvp[cc], wqa = wqp[cc], wka = wkp[cc];  // wave-uniform -> s_load
      av0 = fmaf(xv.x, wva, av0); av1 = fmaf(xv.y, wva, av1);
      av2 = fmaf(xv.z, wva, av2); av3 = fmaf(xv.w, wva, av3);
      aq0 = fmaf(xv.x, wqa, aq0); aq1 = fmaf(xv.y, wqa, aq1);
      aq2 = fmaf(xv.z, wqa, aq2); aq3 = fmaf(xv.w, wqa, aq3);
      ak0 = fmaf(xv.x, wka, ak0); ak1 = fmaf(xv.y, wka, ak1);
      ak2 = fmaf(xv.z, wka, ak2); ak3 = fmaf(xv.w, wka, ak3);
    }
    const int row = p4 / TS;
    const int col = p4 - row * TS;
    uint16_t* vp = &Vs[row * TS + col];
    vp[0] = f2bf(av0); vp[1] = f2bf(av1); vp[2] = f2bf(av2); vp[3] = f2bf(av3);
    uint16_t* qp = &Qs[row * KST + col];
    qp[0] = f2bf(aq0); qp[1] = f2bf(aq1); qp[2] = f2bf(aq2); qp[3] = f2bf(aq3);
    uint16_t* kp = &Ks[row * KST + col];
    kp[0] = f2bf(ak0); kp[1] = f2bf(ak1); kp[2] = f2bf(ak2); kp[3] = f2bf(ak3);
  }
  __syncthreads();

  // ---- attention: each wave owns 24 x-rows, processed 4 at a time ----
  const int lane  = t & 63;
  const int w     = t >> 6;
  const int z2row = 64 + (lane & 31);    // second z slot (valid for lanes 0..31)
  const bool hasz2 = (lane < 32);
  float* __restrict__ attn_base = attn_out + (size_t)((b * 64 + c) * 8 + h) * TSS;
  const float inv_sc = 1.0f / 9216.0f;

  for (int g = 0; g < 6; ++g) {
    const int x0 = w * 24 + g * 4;
    // scores S[x0+r][z] = sum_y V[x][y] * K[z][y] / 9216
    float s1[4] = {0.f,0.f,0.f,0.f};
    float s2[4] = {0.f,0.f,0.f,0.f};
    for (int y = 0; y < TS; y += 8) {
      float kf1[8], kf2[8];
      unpack8(*(const uint4*)&Ks[lane * KST + y], kf1);
      unpack8(*(const uint4*)&Ks[z2row * KST + y], kf2);
      #pragma unroll
      for (int r = 0; r < 4; ++r) {
        float vf[8];
        unpack8(*(const uint4*)&Vs[(x0 + r) * TS + y], vf);  // broadcast
        #pragma unroll
        for (int j = 0; j < 8; ++j) {
          s1[r] = fmaf(vf[j], kf1[j], s1[r]);
          s2[r] = fmaf(vf[j], kf2[j], s2[r]);
        }
      }
    }
    // softmax over z (96 entries: z=lane across 64 lanes, z=64+lane for lanes<32)
    #pragma unroll
    for (int r = 0; r < 4; ++r) {
      const float a1 = s1[r] * inv_sc;
      const float a2 = s2[r] * inv_sc;
      float m = hasz2 ? fmaxf(a1, a2) : a1;
      #pragma unroll
      for (int off = 32; off > 0; off >>= 1) m = fmaxf(m, __shfl_xor(m, off, 64));
      const float e1 = expf(a1 - m);
      const float e2 = hasz2 ? expf(a2 - m) : 0.f;
      float ss = e1 + e2;
      #pragma unroll
      for (int off = 32; off > 0; off >>= 1) ss += __shfl_xor(ss, off, 64);
      const float inv = 1.0f / ss;
      hrow[w][r][lane] = e1 * inv;
      if (hasz2) hrow[w][r][64 + lane] = e2 * inv;
    }
    // PV: o[x][z] = sum_y h[x][y] * Q[z][y]
    float o1[4] = {0.f,0.f,0.f,0.f};
    float o2[4] = {0.f,0.f,0.f,0.f};
    for (int y = 0; y < TS; y += 8) {
      float qf1[8], qf2[8];
      unpack8(*(const uint4*)&Qs[lane * KST + y], qf1);
      unpack8(*(const uint4*)&Qs[z2row * KST + y], qf2);
      #pragma unroll
      for (int r = 0; r < 4; ++r) {
        const float4 ha = *(const float4*)&hrow[w][r][y];
        const float4 hb = *(const float4*)&hrow[w][r][y + 4];
        o1[r] = fmaf(ha.x, qf1[0], o1[r]); o2[r] = fmaf(ha.x, qf2[0], o2[r]);
        o1[r] = fmaf(ha.y, qf1[1], o1[r]); o2[r] = fmaf(ha.y, qf2[1], o2[r]);
        o1[r] = fmaf(ha.z, qf1[2], o1[r]); o2[r] = fmaf(ha.z, qf2[2], o2[r]);
        o1[r] = fmaf(ha.w, qf1[3], o1[r]); o2[r] = fmaf(ha.w, qf2[3], o2[r]);
        o1[r] = fmaf(hb.x, qf1[4], o1[r]); o2[r] = fmaf(hb.x, qf2[4], o2[r]);
        o1[r] = fmaf(hb.y, qf1[5], o1[r]); o2[r] = fmaf(hb.y, qf2[5], o2[r]);
        o1[r] = fmaf(hb.z, qf1[6], o1[r]); o2[r] = fmaf(hb.z, qf2[6], o2[r]);
        o1[r] = fmaf(hb.w, qf1[7], o1[r]); o2[r] = fmaf(hb.w, qf2[7], o2[r]);
      }
    }
    #pragma unroll
    for (int r = 0; r < 4; ++r) {
      attn_base[(x0 + r) * TS + lane] = o1[r];
      if (hasz2) attn_base[(x0 + r) * TS + 64 + lane] = o2[r];
    }
  }
}

// out[b][o][p] = b_out[o] + sum_k attn[b][k][p] * w_out[o][k]
// lane = spatial p, each wave covers 16 output channels (weights via scalar loads).
__global__ __launch_bounds__(256, 4) void out_proj_kernel(
    const float* __restrict__ attn, const float* __restrict__ w_out,
    const float* __restrict__ b_out, float* __restrict__ out)
{
  const int t  = threadIdx.x;
  const int og = __builtin_amdgcn_readfirstlane(t >> 6) * 16;  // wave-uniform o base
  const int blk = blockIdx.x;          // 576 = 4 batches * 144 p-tiles
  const int b  = blk / 144;
  const int p  = (blk - b * 144) * 64 + (t & 63);
  const float* __restrict__ ap = attn + (size_t)b * 512 * TSS + p;

  float acc[16];
  #pragma unroll
  for (int o = 0; o < 16; ++o) acc[o] = 0.f;

  #pragma unroll 4
  for (int k = 0; k < 512; ++k) {
    const float a = ap[(size_t)k * TSS];
    #pragma unroll
    for (int o = 0; o < 16; ++o)
      acc[o] = fmaf(a, w_out[(og + o) * 512 + k], acc[o]);  // uniform -> s_load
  }

  float* __restrict__ op = out + ((size_t)b * 64 + og) * TSS + p;
  #pragma unroll
  for (int o = 0; o < 16; ++o)
    op[(size_t)o * TSS] = acc[o] + b_out[og + o];
}

extern "C" void kernel_launch(void* const* d_in, const int* in_sizes, int n_in,
                              void* d_out, int out_size, void* d_ws, size_t ws_size,
                              hipStream_t stream) {
  const float* x     = (const float*)d_in[0];
  const float* w_vkq = (const float*)d_in[1];
  const float* b_vkq = (const float*)d_in[2];
  const float* w_out = (const float*)d_in[3];
  const float* b_out = (const float*)d_in[4];
  float* out  = (float*)d_out;
  float* attn = (float*)d_ws;   // 4*512*9216 fp32 = 75.5 MB scratch

  attn_fused_kernel<<<dim3(2048), dim3(256), 0, stream>>>(x, w_vkq, b_vkq, attn);
  out_proj_kernel<<<dim3(576), dim3(256), 0, stream>>>(attn, w_out, b_out, out);
}

// Round 2
// 571.299 us; speedup vs baseline: 7.4449x; 7.4449x over previous
//
#include <hip/hip_runtime.h>
#include <cstdint>
#include <cstddef>

#define TS 96
#define TSS 9216
#define CIN 64
#define KST 104   // padded bf16 row stride for K/Q (16B-aligned rows for b128 reads)

typedef float f32x8 __attribute__((ext_vector_type(8)));
typedef float f32x4 __attribute__((ext_vector_type(4)));

__device__ __forceinline__ uint16_t f2bf(float x) {
  uint32_t u = __float_as_uint(x);
  return (uint16_t)((u + 0x7fffu + ((u >> 16) & 1u)) >> 16);  // RNE
}

// SSA-friendly unpack: returns ext-vector BY VALUE (no stack arrays -> no scratch)
__device__ __forceinline__ f32x8 unpack8(uint4 u) {
  f32x8 f;
  f[0] = __uint_as_float(u.x << 16);
  f[1] = __uint_as_float(u.x & 0xffff0000u);
  f[2] = __uint_as_float(u.y << 16);
  f[3] = __uint_as_float(u.y & 0xffff0000u);
  f[4] = __uint_as_float(u.z << 16);
  f[5] = __uint_as_float(u.z & 0xffff0000u);
  f[6] = __uint_as_float(u.w << 16);
  f[7] = __uint_as_float(u.w & 0xffff0000u);
  return f;
}

// One block per (b, h, c): project v,q,k (fp32 -> bf16 LDS), scores, softmax, PV.
// attn_out layout: [b][c*8+h][x][z]  (matches reference transpose(0,2,1,3,4))
__global__ __launch_bounds__(256, 2) void attn_fused_kernel(
    const float* __restrict__ x, const float* __restrict__ w_vkq,
    const float* __restrict__ b_vkq, float* __restrict__ attn_out)
{
  __shared__ __align__(16) uint16_t Vs[TS * TS];    // 18432 B, broadcast reads
  __shared__ __align__(16) uint16_t Ks[TS * KST];   // 19968 B, per-lane row reads
  __shared__ __align__(16) uint16_t Qs[TS * KST];   // 19968 B
  __shared__ __align__(16) float hrow[4][4][TS];    // 6144 B, per-wave softmax rows
  // total 64512 B < 64 KiB static limit; 2 blocks/CU

  const int t   = threadIdx.x;
  const int blk = blockIdx.x;
  const int b   = blk >> 9;      // 512 blocks per batch (b-major -> co-scheduled blocks share x[b] in L2)
  const int hc  = blk & 511;     // h*64 + c
  const int h   = hc >> 6;
  const int c   = hc & 63;

  const float bv = b_vkq[hc];
  const float bq = b_vkq[512 + hc];
  const float bk = b_vkq[1024 + hc];
  const float* __restrict__ wvp = w_vkq + (size_t)hc * CIN;            // s=0 (v)
  const float* __restrict__ wqp = w_vkq + (size_t)(512 + hc) * CIN;    // s=1 (q)
  const float* __restrict__ wkp = w_vkq + (size_t)(1024 + hc) * CIN;   // s=2 (k)
  const float* __restrict__ xb  = x + (size_t)b * CIN * TSS;

  // ---- projection: v,q,k for all 9216 spatial positions (fp32 FMA) ----
  for (int sweep = 0; sweep < 9; ++sweep) {
    const int p4 = sweep * 1024 + t * 4;   // 4 consecutive positions, row-aligned (96%4==0)
    float av0=bv, av1=bv, av2=bv, av3=bv;
    float aq0=bq, aq1=bq, aq2=bq, aq3=bq;
    float ak0=bk, ak1=bk, ak2=bk, ak3=bk;
    #pragma unroll 4
    for (int cc = 0; cc < CIN; ++cc) {
      const float4 xv = *(const float4*)(xb + (size_t)cc * TSS + p4);
      const float wva = wvp[cc], wqa = wqp[cc], wka = wkp[cc];  // wave-uniform -> s_load
      av0 = fmaf(xv.x, wva, av0); av1 = fmaf(xv.y, wva, av1);
      av2 = fmaf(xv.z, wva, av2); av3 = fmaf(xv.w, wva, av3);
      aq0 = fmaf(xv.x, wqa, aq0); aq1 = fmaf(xv.y, wqa, aq1);
      aq2 = fmaf(xv.z, wqa, aq2); aq3 = fmaf(xv.w, wqa, aq3);
      ak0 = fmaf(xv.x, wka, ak0); ak1 = fmaf(xv.y, wka, ak1);
      ak2 = fmaf(xv.z, wka, ak2); ak3 = fmaf(xv.w, wka, ak3);
    }
    const int row = p4 / TS;
    const int col = p4 - row * TS;
    uint16_t* vp = &Vs[row * TS + col];
    vp[0] = f2bf(av0); vp[1] = f2bf(av1); vp[2] = f2bf(av2); vp[3] = f2bf(av3);
    uint16_t* qp = &Qs[row * KST + col];
    qp[0] = f2bf(aq0); qp[1] = f2bf(aq1); qp[2] = f2bf(aq2); qp[3] = f2bf(aq3);
    uint16_t* kp = &Ks[row * KST + col];
    kp[0] = f2bf(ak0); kp[1] = f2bf(ak1); kp[2] = f2bf(ak2); kp[3] = f2bf(ak3);
  }
  __syncthreads();

  // ---- attention: each wave owns 24 x-rows, processed 4 at a time ----
  const int lane  = t & 63;
  const int w     = t >> 6;
  const int z2row = 64 + (lane & 31);    // second z slot (lanes>=32 duplicate lanes 0..31; harmless)
  const bool hasz2 = (lane < 32);
  float* __restrict__ attn_base = attn_out + (size_t)((b * 64 + c) * 8 + h) * TSS;
  const float inv_sc = 1.0f / 9216.0f;
  const float log2e  = 1.44269504088896f;

  for (int g = 0; g < 6; ++g) {
    const int x0 = w * 24 + g * 4;
    // scores S[x0+r][z] = sum_y V[x][y] * K[z][y] / 9216
    f32x4 s1 = {0.f,0.f,0.f,0.f};
    f32x4 s2 = {0.f,0.f,0.f,0.f};
    #pragma unroll 2
    for (int y = 0; y < TS; y += 8) {
      const f32x8 kf1 = unpack8(*(const uint4*)&Ks[lane * KST + y]);
      const f32x8 kf2 = unpack8(*(const uint4*)&Ks[z2row * KST + y]);
      #pragma unroll
      for (int r = 0; r < 4; ++r) {
        const f32x8 vf = unpack8(*(const uint4*)&Vs[(x0 + r) * TS + y]);  // broadcast
        float a1 = s1[r], a2 = s2[r];
        #pragma unroll
        for (int j = 0; j < 8; ++j) {
          a1 = fmaf(vf[j], kf1[j], a1);
          a2 = fmaf(vf[j], kf2[j], a2);
        }
        s1[r] = a1; s2[r] = a2;
      }
    }
    // softmax over z (96 entries: z=lane across 64 lanes, z=64+lane for lanes<32)
    #pragma unroll
    for (int r = 0; r < 4; ++r) {
      const float a1 = s1[r] * inv_sc;
      const float a2 = s2[r] * inv_sc;
      float m = fmaxf(a1, a2);   // lanes>=32 see duplicated a2 -> max unchanged
      #pragma unroll
      for (int off = 32; off > 0; off >>= 1) m = fmaxf(m, __shfl_xor(m, off, 64));
      const float e1 = __builtin_exp2f((a1 - m) * log2e);
      const float e2 = hasz2 ? __builtin_exp2f((a2 - m) * log2e) : 0.f;
      float ss = e1 + e2;
      #pragma unroll
      for (int off = 32; off > 0; off >>= 1) ss += __shfl_xor(ss, off, 64);
      const float inv = 1.0f / ss;
      hrow[w][r][lane] = e1 * inv;
      if (hasz2) hrow[w][r][64 + lane] = e2 * inv;
    }
    // PV: o[x][z] = sum_y h[x][y] * Q[z][y]
    f32x4 o1 = {0.f,0.f,0.f,0.f};
    f32x4 o2 = {0.f,0.f,0.f,0.f};
    #pragma unroll 2
    for (int y = 0; y < TS; y += 8) {
      const f32x8 qf1 = unpack8(*(const uint4*)&Qs[lane * KST + y]);
      const f32x8 qf2 = unpack8(*(const uint4*)&Qs[z2row * KST + y]);
      #pragma unroll
      for (int r = 0; r < 4; ++r) {
        const float4 ha = *(const float4*)&hrow[w][r][y];      // broadcast
        const float4 hb = *(const float4*)&hrow[w][r][y + 4];
        float a1 = o1[r], a2 = o2[r];
        a1 = fmaf(ha.x, qf1[0], a1); a2 = fmaf(ha.x, qf2[0], a2);
        a1 = fmaf(ha.y, qf1[1], a1); a2 = fmaf(ha.y, qf2[1], a2);
        a1 = fmaf(ha.z, qf1[2], a1); a2 = fmaf(ha.z, qf2[2], a2);
        a1 = fmaf(ha.w, qf1[3], a1); a2 = fmaf(ha.w, qf2[3], a2);
        a1 = fmaf(hb.x, qf1[4], a1); a2 = fmaf(hb.x, qf2[4], a2);
        a1 = fmaf(hb.y, qf1[5], a1); a2 = fmaf(hb.y, qf2[5], a2);
        a1 = fmaf(hb.z, qf1[6], a1); a2 = fmaf(hb.z, qf2[6], a2);
        a1 = fmaf(hb.w, qf1[7], a1); a2 = fmaf(hb.w, qf2[7], a2);
        o1[r] = a1; o2[r] = a2;
      }
    }
    #pragma unroll
    for (int r = 0; r < 4; ++r) {
      attn_base[(x0 + r) * TS + lane] = o1[r];
      if (hasz2) attn_base[(x0 + r) * TS + 64 + lane] = o2[r];
    }
  }
}

// out[b][o][p] = b_out[o] + sum_k attn[b][k][p] * w_out[o][k]
// lane = spatial p, each wave covers 16 output channels (weights via scalar loads).
__global__ __launch_bounds__(256, 4) void out_proj_kernel(
    const float* __restrict__ attn, const float* __restrict__ w_out,
    const float* __restrict__ b_out, float* __restrict__ out)
{
  const int t  = threadIdx.x;
  const int og = __builtin_amdgcn_readfirstlane(t >> 6) * 16;  // wave-uniform o base
  const int blk = blockIdx.x;          // 576 = 4 batches * 144 p-tiles
  const int b  = blk / 144;
  const int p  = (blk - b * 144) * 64 + (t & 63);
  const float* __restrict__ ap = attn + (size_t)b * 512 * TSS + p;

  float acc[16];
  #pragma unroll
  for (int o = 0; o < 16; ++o) acc[o] = 0.f;

  #pragma unroll 4
  for (int k = 0; k < 512; ++k) {
    const float a = ap[(size_t)k * TSS];
    #pragma unroll
    for (int o = 0; o < 16; ++o)
      acc[o] = fmaf(a, w_out[(og + o) * 512 + k], acc[o]);  // uniform -> s_load
  }

  float* __restrict__ op = out + ((size_t)b * 64 + og) * TSS + p;
  #pragma unroll
  for (int o = 0; o < 16; ++o)
    op[(size_t)o * TSS] = acc[o] + b_out[og + o];
}

extern "C" void kernel_launch(void* const* d_in, const int* in_sizes, int n_in,
                              void* d_out, int out_size, void* d_ws, size_t ws_size,
                              hipStream_t stream) {
  const float* x     = (const float*)d_in[0];
  const float* w_vkq = (const float*)d_in[1];
  const float* b_vkq = (const float*)d_in[2];
  const float* w_out = (const float*)d_in[3];
  const float* b_out = (const float*)d_in[4];
  float* out  = (float*)d_out;
  float* attn = (float*)d_ws;   // 4*512*9216 fp32 = 75.5 MB scratch

  attn_fused_kernel<<<dim3(2048), dim3(256), 0, stream>>>(x, w_vkq, b_vkq, attn);
  out_proj_kernel<<<dim3(576), dim3(256), 0, stream>>>(attn, w_out, b_out, out);
}

// Round 3
// 202.447 us; speedup vs baseline: 21.0093x; 2.8220x over previous
//
#include <hip/hip_runtime.h>
#include <cstdint>
#include <cstddef>

typedef float f32x4 __attribute__((ext_vector_type(4)));
typedef __bf16 bf16x8 __attribute__((ext_vector_type(8)));

#define TSS 9216
#define KST 104   // attn LDS row stride (bf16): 208B=52 banks => 2-way floor on frag reads
#define PST 72    // proj LDS row stride (bf16): 144B=36 banks => 2-way floor

__device__ __forceinline__ uint16_t f2bf(float x) {
  uint32_t u = __float_as_uint(x);
  return (uint16_t)((u + 0x7fffu + ((u >> 16) & 1u)) >> 16);  // RNE
}
__device__ __forceinline__ float bflo(uint32_t u) { return __uint_as_float(u << 16); }
__device__ __forceinline__ float bfhi(uint32_t u) { return __uint_as_float(u & 0xffff0000u); }

// ---------------- Kernel 1: vqk[b][o][p] = sum_c W[o][c] X[b][c][p] + bias[o] ----------------
// MFMA bf16 16x16x32, 128x128 block tile, 4 waves (2x2 of 64x64), K=64 (2 k-steps).
// grid: blk = (b*72 + nt)*12 + mt  -> 12 consecutive blocks share one X B-tile (L2).
__global__ __launch_bounds__(256, 2) void proj_kernel(
    const float* __restrict__ x, const float* __restrict__ w_vkq,
    const float* __restrict__ b_vkq, uint16_t* __restrict__ vqk)
{
  __shared__ __align__(16) uint16_t Al[128 * PST];  // W tile [o][c]
  __shared__ __align__(16) uint16_t Bt[128 * PST];  // X tile transposed [p][c]

  const int t  = threadIdx.x;
  const int blk = blockIdx.x;
  const int mt = blk % 12;
  const int bn = blk / 12;
  const int nt = bn % 72;
  const int b  = bn / 72;
  const int m0 = mt * 128, n0 = nt * 128;

  // stage A: W[m0..+127][0..63] fp32 -> bf16, coalesced float4
  {
    const float4* src = (const float4*)(w_vkq + (size_t)m0 * 64);
    #pragma unroll
    for (int i = 0; i < 8; ++i) {
      const int idx = t + i * 256;          // 2048 float4 total
      const int row = idx >> 4;             // 16 float4 per 64-col row
      const int c4  = (idx & 15) * 4;
      const float4 v = src[idx];
      uint16_t* dst = &Al[row * PST + c4];
      dst[0] = f2bf(v.x); dst[1] = f2bf(v.y); dst[2] = f2bf(v.z); dst[3] = f2bf(v.w);
    }
  }
  // stage B transposed: X[b][c][n0+p] -> Bt[p][c]; lane-consecutive p => coalesced dwords
  {
    const float* __restrict__ xb = x + (size_t)b * 64 * TSS + n0;
    const int p  = t & 127;
    const int c0 = (t >> 7) * 32;
    float v[32];
    #pragma unroll
    for (int i = 0; i < 32; ++i) v[i] = xb[(size_t)(c0 + i) * TSS + p];
    #pragma unroll
    for (int i4 = 0; i4 < 8; ++i4) {
      const uint32_t lo = (uint32_t)f2bf(v[i4*4+0]) | ((uint32_t)f2bf(v[i4*4+1]) << 16);
      const uint32_t hi = (uint32_t)f2bf(v[i4*4+2]) | ((uint32_t)f2bf(v[i4*4+3]) << 16);
      uint2 pk; pk.x = lo; pk.y = hi;
      *(uint2*)&Bt[p * PST + c0 + i4 * 4] = pk;
    }
  }
  __syncthreads();

  const int L    = t & 63;
  const int w    = t >> 6;
  const int wm   = (w >> 1) * 64;
  const int wn   = (w & 1) * 64;
  const int lcol = L & 15;
  const int lq   = L >> 4;

  const f32x4 zero4 = {0.f, 0.f, 0.f, 0.f};
  f32x4 acc[4][4];
  #pragma unroll
  for (int i = 0; i < 4; ++i)
    #pragma unroll
    for (int j = 0; j < 4; ++j) acc[i][j] = zero4;

  #pragma unroll
  for (int ks = 0; ks < 2; ++ks) {
    bf16x8 af[4], bfr[4];
    #pragma unroll
    for (int tm = 0; tm < 4; ++tm)
      af[tm] = *(const bf16x8*)&Al[(wm + tm*16 + lcol) * PST + ks*32 + lq*8];
    #pragma unroll
    for (int tn = 0; tn < 4; ++tn)
      bfr[tn] = *(const bf16x8*)&Bt[(wn + tn*16 + lcol) * PST + ks*32 + lq*8];
    #pragma unroll
    for (int tm = 0; tm < 4; ++tm)
      #pragma unroll
      for (int tn = 0; tn < 4; ++tn)
        acc[tm][tn] = __builtin_amdgcn_mfma_f32_16x16x32_bf16(af[tm], bfr[tn], acc[tm][tn], 0, 0, 0);
  }

  float bias[4][4];
  #pragma unroll
  for (int tm = 0; tm < 4; ++tm)
    #pragma unroll
    for (int r = 0; r < 4; ++r)
      bias[tm][r] = b_vkq[m0 + wm + tm*16 + lq*4 + r];

  uint16_t* __restrict__ outb = vqk + (size_t)(b*1536 + m0 + wm) * TSS + n0 + wn;
  #pragma unroll
  for (int tm = 0; tm < 4; ++tm)
    #pragma unroll
    for (int tn = 0; tn < 4; ++tn)
      #pragma unroll
      for (int r = 0; r < 4; ++r) {
        const int row = tm*16 + lq*4 + r;
        const int col = tn*16 + lcol;
        outb[(size_t)row * TSS + col] = f2bf(acc[tm][tn][r] + bias[tm][r]);
      }
}

// ---------------- Kernel 2: per-(b,hc) attention, MFMA, output in-place over V plane ----------
// 384 threads = 6 waves; wave w owns x-strip [16w..16w+15].
__global__ __launch_bounds__(384, 3) void attn_kernel(uint16_t* __restrict__ vqk)
{
  __shared__ __align__(16) uint16_t Vs[96 * KST];  // V, later reused per-wave for P
  __shared__ __align__(16) uint16_t Ks[96 * KST];
  __shared__ __align__(16) uint16_t Qs[96 * KST];

  const int t   = threadIdx.x;
  const int blk = blockIdx.x;
  const int b   = blk >> 9;
  const int hc  = blk & 511;

  // stage 3 planes (each 9216 bf16 contiguous); 1152 uint4 groups per plane, 3/thread
  {
    const size_t pbase = (size_t)(b * 1536 + hc) * TSS;
    const uint4* __restrict__ sv = (const uint4*)(vqk + pbase);                 // V: o=hc
    const uint4* __restrict__ sk = (const uint4*)(vqk + pbase + (size_t)1024 * TSS);  // K: o=1024+hc
    const uint4* __restrict__ sq = (const uint4*)(vqk + pbase + (size_t)512  * TSS);  // Q: o=512+hc
    #pragma unroll
    for (int i = 0; i < 3; ++i) {
      const int g   = t + i * 384;
      const int row = g / 12;
      const int off = (g - row * 12) * 8;   // bf16 offset within row
      *(uint4*)&Vs[row * KST + off] = sv[g];
      *(uint4*)&Ks[row * KST + off] = sk[g];
      *(uint4*)&Qs[row * KST + off] = sq[g];
    }
  }
  __syncthreads();

  const int L    = t & 63;
  const int w    = t / 64;       // 0..5
  const int lcol = L & 15;
  const int lq   = L >> 4;
  const int xr   = 16 * w;
  const float inv_sc = 1.0f / 9216.0f;
  const float log2e  = 1.44269504088896f;
  const f32x4 zero4 = {0.f, 0.f, 0.f, 0.f};

  // scores S[x][z] = sum_y V[x][y] K[z][y]
  f32x4 sa[6];
  #pragma unroll
  for (int i = 0; i < 6; ++i) sa[i] = zero4;
  bf16x8 av[3];
  #pragma unroll
  for (int ks = 0; ks < 3; ++ks)
    av[ks] = *(const bf16x8*)&Vs[(xr + lcol) * KST + ks*32 + lq*8];
  #pragma unroll
  for (int tz = 0; tz < 6; ++tz) {
    #pragma unroll
    for (int ks = 0; ks < 3; ++ks) {
      const bf16x8 bk = *(const bf16x8*)&Ks[(tz*16 + lcol) * KST + ks*32 + lq*8];
      sa[tz] = __builtin_amdgcn_mfma_f32_16x16x32_bf16(av[ks], bk, sa[tz], 0, 0, 0);
    }
  }

  // softmax over z: regs hold [tz][r] at col=lcol; reduce across tz then across 16-lane col group
  float p_[6][4];
  #pragma unroll
  for (int r = 0; r < 4; ++r) {
    float a[6];
    #pragma unroll
    for (int tz = 0; tz < 6; ++tz) a[tz] = sa[tz][r] * inv_sc;
    float m = a[0];
    #pragma unroll
    for (int tz = 1; tz < 6; ++tz) m = fmaxf(m, a[tz]);
    #pragma unroll
    for (int off = 8; off > 0; off >>= 1) m = fmaxf(m, __shfl_xor(m, off, 64));
    float s = 0.f;
    #pragma unroll
    for (int tz = 0; tz < 6; ++tz) { const float e = __builtin_exp2f((a[tz] - m) * log2e); p_[tz][r] = e; s += e; }
    #pragma unroll
    for (int off = 8; off > 0; off >>= 1) s += __shfl_xor(s, off, 64);
    const float inv = 1.0f / s;
    #pragma unroll
    for (int tz = 0; tz < 6; ++tz) p_[tz][r] *= inv;
  }

  // P -> bf16 into own strip of Vs (wave-private rows; in-wave ds order is program order)
  #pragma unroll
  for (int tz = 0; tz < 6; ++tz)
    #pragma unroll
    for (int r = 0; r < 4; ++r)
      Vs[(xr + lq*4 + r) * KST + tz*16 + lcol] = f2bf(p_[tz][r]);

  // O[x][z'] = sum_y P[x][y] Q[z'][y]
  f32x4 oa[6];
  #pragma unroll
  for (int i = 0; i < 6; ++i) oa[i] = zero4;
  bf16x8 ap[3];
  #pragma unroll
  for (int ks = 0; ks < 3; ++ks)
    ap[ks] = *(const bf16x8*)&Vs[(xr + lcol) * KST + ks*32 + lq*8];
  #pragma unroll
  for (int tz = 0; tz < 6; ++tz) {
    #pragma unroll
    for (int ks = 0; ks < 3; ++ks) {
      const bf16x8 bq = *(const bf16x8*)&Qs[(tz*16 + lcol) * KST + ks*32 + lq*8];
      oa[tz] = __builtin_amdgcn_mfma_f32_16x16x32_bf16(ap[ks], bq, oa[tz], 0, 0, 0);
    }
  }

  // store O bf16 over this block's own V plane
  uint16_t* __restrict__ dst = vqk + (size_t)(b * 1536 + hc) * TSS;
  #pragma unroll
  for (int tz = 0; tz < 6; ++tz)
    #pragma unroll
    for (int r = 0; r < 4; ++r)
      dst[(xr + lq*4 + r) * 96 + tz*16 + lcol] = f2bf(oa[tz][r]);
}

// ---------------- Kernel 3: out[b][o][p] = b_out[o] + sum_k attn[b][plane(k)][p] w_out[o][k] ---
// plane(k) = (k&7)*64 + (k>>3)  (k = c*8+h  <->  plane hc = h*64+c)
__global__ __launch_bounds__(256, 4) void out_proj_kernel(
    const uint16_t* __restrict__ attn, const float* __restrict__ w_out,
    const float* __restrict__ b_out, float* __restrict__ out)
{
  const int t  = threadIdx.x;
  const int L  = t & 63;
  const int og = __builtin_amdgcn_readfirstlane(t >> 6) * 16;
  const int blk = blockIdx.x;      // 288 = 4b * 72 p-tiles
  const int b  = blk / 72;
  const int p0 = (blk - b * 72) * 128 + L * 2;
  const uint16_t* __restrict__ ab = attn + (size_t)b * 1536 * TSS + p0;

  float acc0[16], acc1[16];
  #pragma unroll
  for (int o = 0; o < 16; ++o) { acc0[o] = 0.f; acc1[o] = 0.f; }

  #pragma unroll 8
  for (int k = 0; k < 512; ++k) {
    const int plane = ((k & 7) << 6) | (k >> 3);
    const uint32_t u = *(const uint32_t*)(ab + (size_t)plane * TSS);
    const float a0 = bflo(u), a1 = bfhi(u);
    #pragma unroll
    for (int o = 0; o < 16; ++o) {
      const float wv = w_out[(og + o) * 512 + k];   // wave-uniform -> s_load
      acc0[o] = fmaf(a0, wv, acc0[o]);
      acc1[o] = fmaf(a1, wv, acc1[o]);
    }
  }

  #pragma unroll
  for (int o = 0; o < 16; ++o) {
    const float bo = b_out[og + o];
    float2 st; st.x = acc0[o] + bo; st.y = acc1[o] + bo;
    *(float2*)(out + (size_t)(b * 64 + og + o) * TSS + p0) = st;
  }
}

extern "C" void kernel_launch(void* const* d_in, const int* in_sizes, int n_in,
                              void* d_out, int out_size, void* d_ws, size_t ws_size,
                              hipStream_t stream) {
  const float* x     = (const float*)d_in[0];
  const float* w_vkq = (const float*)d_in[1];
  const float* b_vkq = (const float*)d_in[2];
  const float* w_out = (const float*)d_in[3];
  const float* b_out = (const float*)d_in[4];
  float* out = (float*)d_out;
  uint16_t* vqk = (uint16_t*)d_ws;   // 4*1536*9216 bf16 = 113.2 MB

  proj_kernel<<<dim3(3456), dim3(256), 0, stream>>>(x, w_vkq, b_vkq, vqk);
  attn_kernel<<<dim3(2048), dim3(384), 0, stream>>>(vqk);
  out_proj_kernel<<<dim3(288), dim3(256), 0, stream>>>(vqk, w_out, b_out, out);
}